// Round 6
// baseline (208.681 us; speedup 1.0000x reference)
//
#include <hip/hip_runtime.h>
#include <stdint.h>

typedef __bf16 bf16x8 __attribute__((ext_vector_type(8)));
typedef __bf16 bf16x4v __attribute__((ext_vector_type(4)));
typedef float  f32x16 __attribute__((ext_vector_type(16)));
typedef float  f32x4t __attribute__((ext_vector_type(4)));
typedef unsigned int u32x2 __attribute__((ext_vector_type(2)));

// ---- ws layout (bytes) ----
#define WS_W1S 0            // 32 chunks  * 1 KB = 32 KB   W1e fragment-swizzled
#define WS_W2S 32768        // 128 chunks * 1 KB = 128 KB  W2 fragment-swizzled
#define WS_R   163840       // 4*256*256 f32 = 1 MiB   Rt[b][n][o] (incl. b1)
#define WS_CT  1212416      // 4*256*256 bf16 = 512 KB Cts fragment-swizzled

// ---------------- pre-kernel 1: weights -> bf16, MFMA-fragment-swizzled ----
// o = wid*64 + mb*32 + (lane&31), k = ks*16 + (lane>>5)*8 + j.
__global__ void prep_weights(const float* __restrict__ W1, const float* __restrict__ W2,
                             __bf16* __restrict__ w1s, __bf16* __restrict__ w2s) {
    int t = blockIdx.x * 256 + threadIdx.x;
    int chunk = t >> 6, lane = t & 63;
    if (chunk < 128) {                        // W2: 4 wid x 16 ks x 2 mb
        int wid = chunk >> 5, ks = (chunk >> 1) & 15, mb = chunk & 1;
        int o = wid * 64 + mb * 32 + (lane & 31);
        int k = ks * 16 + (lane >> 5) * 8;
        const float* src = W2 + o * 256 + k;
        __bf16* dst = w2s + chunk * 512 + lane * 8;
#pragma unroll
        for (int j = 0; j < 8; ++j) dst[j] = (__bf16)src[j];
    } else if (chunk < 160) {                 // W1e: 4 wid x 4 ks x 2 mb
        int c1 = chunk - 128;
        int wid = c1 >> 3, ks = (c1 >> 1) & 3, mb = c1 & 1;
        int o = wid * 64 + mb * 32 + (lane & 31);
        int k = ks * 16 + (lane >> 5) * 8;
        const float* src = W1 + o * 320 + k;
        __bf16* dst = w1s + c1 * 512 + lane * 8;
#pragma unroll
        for (int j = 0; j < 8; ++j) dst[j] = (__bf16)src[j];
    }
}

// ---------------- pre-kernel 2: R/C rank-1 terms ----------------
// Rt[b][n][o] fp32 (plain, broadcast-read). Cts bf16 fragment-swizzled:
// chunk(b,mg,wid,mb,rg,nbm)*256 + lane*4 + oq; lane = hi*32 + (m&31).
__global__ __launch_bounds__(256) void prep_rc(
    const float* __restrict__ W1, const float* __restrict__ b1,
    const float* __restrict__ node, float* __restrict__ Rt,
    __bf16* __restrict__ Cts) {
    __shared__ float nds[128 * 16];
    const int b = blockIdx.x >> 4, j0 = (blockIdx.x & 15) * 16;
    const int o = threadIdx.x;
    {
        int c = threadIdx.x >> 1, jh = (threadIdx.x & 1) * 8;
        const float* src = node + b * 32768 + c * 256 + j0 + jh;
        *(float4*)&nds[c * 16 + jh] = *(const float4*)src;
        *(float4*)&nds[c * 16 + jh + 4] = *(const float4*)(src + 4);
    }
    __syncthreads();
    float aR[16], aC[16];
#pragma unroll
    for (int j = 0; j < 16; ++j) { aR[j] = 0.f; aC[j] = 0.f; }
    const float* wr = W1 + o * 320 + 64;
    const float* wc = W1 + o * 320 + 192;
    for (int c4 = 0; c4 < 32; ++c4) {
        float4 wrv = *(const float4*)(wr + c4 * 4);
        float4 wcv = *(const float4*)(wc + c4 * 4);
        const float* wrp = (const float*)&wrv;
        const float* wcp = (const float*)&wcv;
#pragma unroll
        for (int r = 0; r < 4; ++r) {
            const f32x4t* nrow = (const f32x4t*)&nds[(c4 * 4 + r) * 16];
            f32x4t n0 = nrow[0], n1 = nrow[1], n2 = nrow[2], n3 = nrow[3];
#pragma unroll
            for (int q = 0; q < 4; ++q) {
                aR[q]      = fmaf(wrp[r], n0[q], aR[q]);
                aR[q + 4]  = fmaf(wrp[r], n1[q], aR[q + 4]);
                aR[q + 8]  = fmaf(wrp[r], n2[q], aR[q + 8]);
                aR[q + 12] = fmaf(wrp[r], n3[q], aR[q + 12]);
                aC[q]      = fmaf(wcp[r], n0[q], aC[q]);
                aC[q + 4]  = fmaf(wcp[r], n1[q], aC[q + 4]);
                aC[q + 8]  = fmaf(wcp[r], n2[q], aC[q + 8]);
                aC[q + 12] = fmaf(wcp[r], n3[q], aC[q + 12]);
            }
        }
    }
    float bb = b1[o];
    const int wid = o >> 6, mb = (o >> 5) & 1, rg = (o >> 3) & 3;
    const int hi = (o >> 2) & 1, oq = o & 3;
#pragma unroll
    for (int j = 0; j < 16; ++j) {
        int m = j0 + j;
        Rt[((b * 256 + m) << 8) + o] = aR[j] + bb;
        int mg = m >> 6, nbm = (m >> 5) & 1, p31m = m & 31;
        int chunk = ((((b * 4 + mg) * 4 + wid) * 2 + mb) * 4 + rg) * 2 + nbm;
        Cts[chunk * 256 + (hi * 32 + p31m) * 4 + oq] = (__bf16)aC[j];
    }
}

// ---------------- main fused kernel ----------------
// 256 thr (4 waves x 64 och), grid 512. Block = (b, m0); 4 iters x 2 n-rows
// = 128-pixel layer-2 tiles: halves W2 L2 traffic, 2x MFMA cover per A2 load.
// A2 streamed in double-buffered sub-quarters (2 k-steps, 32 arch regs);
// acc[2][4] = 128 AGPR. h1 LDS: 512 B rows + 16B-column XOR swizzle ->
// conflict-free b64 writes and b128 reads. asm anti-LICM barriers are
// load-bearing (R2/R3: LICM re-hoists weight loads -> 75 MB scratch spill).
__global__ __launch_bounds__(256, 2) void fused_main(
    const float* __restrict__ edge, const __bf16* __restrict__ w1s,
    const __bf16* __restrict__ w2s, const float* __restrict__ Rt,
    const __bf16* __restrict__ Cts, const float* __restrict__ b2,
    const float* __restrict__ W3, const float* __restrict__ b3,
    float* __restrict__ out) {
    __shared__ unsigned int lds_e[64 * 33];   // 8448 B  edge tile [m][e-pair]
    __shared__ unsigned int lds_h1[128 * 128];// 65536 B h1, xor-swizzled 16B cols
    __shared__ float lds_p[128 * 9];          // 4608 B  layer-3 partials
    __shared__ float lds_c[512];              // 2048 B  b2 | W3
    char* h1b = (char*)lds_h1;

    const int tid = threadIdx.x;
    const int wid = tid >> 6;
    const int lane = tid & 63;
    const int p31 = lane & 31;
    const int hi = lane >> 5;
    const int obase = wid * 64;

    const int blk = blockIdx.x;
    const int b   = blk >> 7;
    const int mg  = (blk >> 5) & 3;
    const int m0  = mg << 6;
    const int n0  = (blk & 31) << 3;

    lds_c[tid] = b2[tid];
    lds_c[256 + tid] = W3[tid];

    const float4* eg = (const float4*)edge;
    const int a_ = tid & 15;
    const int epb = tid >> 4;
    float4 pf[4];

#define PREFETCH(nn)                                                        \
    {                                                                       \
        _Pragma("unroll")                                                   \
        for (int r = 0; r < 2; ++r) {                                       \
            int ep = r * 16 + epb;                                          \
            int f4 = (b * 64 + ep * 2) * 16384 + (nn) * 64 + (m0 >> 2) + a_;\
            pf[r * 2]     = eg[f4];                                         \
            pf[r * 2 + 1] = eg[f4 + 16384];                                 \
        }                                                                   \
    }

#define STAGE_E()                                                           \
    {                                                                       \
        _Pragma("unroll")                                                   \
        for (int r = 0; r < 2; ++r) {                                       \
            int ep = r * 16 + epb;                                          \
            const float* p0 = (const float*)&pf[r * 2];                     \
            const float* p1 = (const float*)&pf[r * 2 + 1];                 \
            _Pragma("unroll")                                               \
            for (int i = 0; i < 4; ++i) {                                   \
                union { __bf16 h[2]; unsigned int u; } t;                   \
                t.h[0] = (__bf16)p0[i];                                     \
                t.h[1] = (__bf16)p1[i];                                     \
                lds_e[(a_ * 4 + i) * 33 + ep] = t.u;                        \
            }                                                               \
        }                                                                   \
    }

    // sub-quarter A2 load: 2 k-steps x 2 mb = 4 coalesced 16 B loads
#define LOADSUB(bf, s)                                                      \
    {                                                                       \
        _Pragma("unroll")                                                   \
        for (int ksl = 0; ksl < 2; ++ksl)                                   \
            _Pragma("unroll")                                               \
            for (int mb = 0; mb < 2; ++mb)                                  \
                A2s[bf][ksl][mb] = *(const bf16x8*)(w2_s +                  \
                    ((((wid << 4) + (s) * 2 + ksl) << 1) + mb) * 512 + (lane << 3)); \
    }

    // layer-1 for one row: acc[mb][nbm] over 64 pixels from lds_e
#define LAYER1()                                                            \
    {                                                                       \
        _Pragma("unroll")                                                   \
        for (int mb = 0; mb < 2; ++mb)                                      \
            _Pragma("unroll")                                               \
            for (int nbm = 0; nbm < 2; ++nbm)                               \
                _Pragma("unroll")                                           \
                for (int k = 0; k < 16; ++k) acc[mb][nbm][k] = 0.f;         \
        _Pragma("unroll")                                                   \
        for (int ks = 0; ks < 4; ++ks) {                                    \
            bf16x8 B1[2];                                                   \
            _Pragma("unroll")                                               \
            for (int nbm = 0; nbm < 2; ++nbm) {                             \
                union { unsigned int u[4]; bf16x8 v; } bb;                  \
                _Pragma("unroll")                                           \
                for (int j = 0; j < 4; ++j)                                 \
                    bb.u[j] = lds_e[(nbm * 32 + p31) * 33 + ks * 8 + hi * 4 + j]; \
                B1[nbm] = bb.v;                                             \
            }                                                               \
            _Pragma("unroll")                                               \
            for (int mb = 0; mb < 2; ++mb) {                                \
                acc[mb][0] = __builtin_amdgcn_mfma_f32_32x32x16_bf16(A1[mb][ks], B1[0], acc[mb][0], 0, 0, 0); \
                acc[mb][1] = __builtin_amdgcn_mfma_f32_32x32x16_bf16(A1[mb][ks], B1[1], acc[mb][1], 0, 0, 0); \
            }                                                               \
        }                                                                   \
    }

    // epilogue-1 for row R: +Rt +Ct, relu, bf16 -> swizzled h1
#define EPI1(R, nn)                                                         \
    {                                                                       \
        const int nRow = (b * 256 + (nn)) << 8;                             \
        _Pragma("unroll")                                                   \
        for (int mb = 0; mb < 2; ++mb) {                                    \
            _Pragma("unroll")                                               \
            for (int rg = 0; rg < 4; ++rg) {                                \
                int och = obase + mb * 32 + 8 * rg + 4 * hi;                \
                f32x4t Rv = *(const f32x4t*)(Rt + nRow + och);              \
                int col16 = (wid << 3) + (mb << 2) + rg;                    \
                _Pragma("unroll")                                           \
                for (int nbm = 0; nbm < 2; ++nbm) {                         \
                    int p = (R) * 64 + nbm * 32 + p31;                      \
                    bf16x4v Cv = CvR[(mb * 4 + rg) * 2 + nbm];              \
                    union { __bf16 h[4]; u32x2 u; } t;                      \
                    _Pragma("unroll")                                       \
                    for (int rr = 0; rr < 4; ++rr) {                        \
                        float v = acc[mb][nbm][rg * 4 + rr] + Rv[rr] + (float)Cv[rr]; \
                        t.h[rr] = (__bf16)fmaxf(v, 0.f);                    \
                    }                                                       \
                    *(u32x2*)(h1b + p * 512 + ((col16 ^ p31) << 4) + (hi << 3)) = t.u; \
                }                                                           \
            }                                                               \
        }                                                                   \
    }

    PREFETCH(n0);

    // ---- hoisted m-invariant Ct fragments: coalesced via swizzled layout ----
    bf16x4v CvR[16];
#pragma unroll
    for (int mb = 0; mb < 2; ++mb)
#pragma unroll
        for (int rg = 0; rg < 4; ++rg)
#pragma unroll
            for (int nbm = 0; nbm < 2; ++nbm) {
                int chunk = ((((b * 4 + mg) * 4 + wid) * 2 + mb) * 4 + rg) * 2 + nbm;
                CvR[(mb * 4 + rg) * 2 + nbm] = *(const bf16x4v*)(Cts + chunk * 256 + lane * 4);
            }

    f32x16 acc[2][4];
    bf16x8 A2s[2][2][2];
#pragma unroll 1
    for (int it = 0; it < 4; ++it) {
        const int n = n0 + it * 2;

        // opaque per-iteration address barriers (defeat LICM/CSE of weight loads)
        uint64_t w1a = (uint64_t)w1s;
        asm volatile("" : "+s"(w1a));
        const __bf16* w1_s = (const __bf16*)w1a;
        uint64_t w2a = (uint64_t)w2s;
        asm volatile("" : "+s"(w2a));
        const __bf16* w2_s = (const __bf16*)w2a;

        STAGE_E();                          // row A from pf
        bf16x8 A1[2][4];
#pragma unroll
        for (int mb = 0; mb < 2; ++mb)
#pragma unroll
            for (int ks = 0; ks < 4; ++ks)
                A1[mb][ks] = *(const bf16x8*)(w1_s +
                    ((((wid << 2) + ks) << 1) + mb) * 512 + (lane << 3));
        __syncthreads();                    // bar1

        PREFETCH(n + 1);                    // row B (covered by L1A)
        LAYER1();
        EPI1(0, n);
        __syncthreads();                    // bar2: lds_e reads done

        STAGE_E();                          // row B
        __syncthreads();                    // bar3

        if (it < 3) PREFETCH(n + 2);        // next iter row A (covered by L1B+L2)
        LAYER1();
        EPI1(1, n + 1);
        __syncthreads();                    // bar4: h1 complete (all waves)

        // ---- layer 2: 128 pixels, A2 streamed in sub-quarters ----
#pragma unroll
        for (int mb = 0; mb < 2; ++mb)
#pragma unroll
            for (int nb = 0; nb < 4; ++nb)
#pragma unroll
                for (int k = 0; k < 16; ++k) acc[mb][nb][k] = 0.f;
        LOADSUB(0, 0);
#pragma unroll
        for (int s = 0; s < 8; ++s) {
            if (s < 7) LOADSUB((s + 1) & 1, s + 1);
#pragma unroll
            for (int ksl = 0; ksl < 2; ++ksl) {
                const int ksg = s * 2 + ksl;
                bf16x8 B2[4];
#pragma unroll
                for (int nb = 0; nb < 4; ++nb) {
                    int p = nb * 32 + p31;
                    B2[nb] = *(const bf16x8*)(h1b + p * 512 +
                             ((((ksg << 1) + hi) ^ p31) << 4));
                }
#pragma unroll
                for (int mb = 0; mb < 2; ++mb)
#pragma unroll
                    for (int nb = 0; nb < 4; ++nb)
                        acc[mb][nb] = __builtin_amdgcn_mfma_f32_32x32x16_bf16(
                            A2s[s & 1][ksl][mb], B2[nb], acc[mb][nb], 0, 0, 0);
            }
        }

        // ---- epilogue 2: +b2, relu, dot W3 ----
        float part[4] = {0.f, 0.f, 0.f, 0.f};
#pragma unroll
        for (int mb = 0; mb < 2; ++mb) {
#pragma unroll
            for (int rg = 0; rg < 4; ++rg) {
                int och = obase + mb * 32 + 8 * rg + 4 * hi;
                f32x4t b2v = *(const f32x4t*)&lds_c[och];
                f32x4t w3v = *(const f32x4t*)&lds_c[256 + och];
#pragma unroll
                for (int rr = 0; rr < 4; ++rr) {
#pragma unroll
                    for (int nb = 0; nb < 4; ++nb) {
                        float h = fmaxf(acc[mb][nb][rg * 4 + rr] + b2v[rr], 0.f);
                        part[nb] = fmaf(w3v[rr], h, part[nb]);
                    }
                }
            }
        }
#pragma unroll
        for (int nb = 0; nb < 4; ++nb)
            lds_p[(nb * 32 + p31) * 9 + wid * 2 + hi] = part[nb];
        __syncthreads();                    // bar5

        if (tid < 128) {
            float s = b3[0];
#pragma unroll
            for (int k = 0; k < 8; ++k) s += lds_p[tid * 9 + k];
            out[((b * 256 + n + (tid >> 6)) << 8) + m0 + (tid & 63)] = s;
        }
        // next-iter lds_e writes don't alias lds_p; bar1 gates next h1 writes.
    }
#undef PREFETCH
#undef STAGE_E
#undef LOADSUB
#undef LAYER1
#undef EPI1
}

extern "C" void kernel_launch(void* const* d_in, const int* in_sizes, int n_in,
                              void* d_out, int out_size, void* d_ws, size_t ws_size,
                              hipStream_t stream) {
    const float* edge = (const float*)d_in[0];
    const float* node = (const float*)d_in[1];
    const float* W1   = (const float*)d_in[2];
    const float* b1   = (const float*)d_in[3];
    const float* W2   = (const float*)d_in[4];
    const float* b2   = (const float*)d_in[5];
    const float* W3   = (const float*)d_in[6];
    const float* b3   = (const float*)d_in[7];
    char* ws = (char*)d_ws;
    __bf16* w1s = (__bf16*)(ws + WS_W1S);
    __bf16* w2s = (__bf16*)(ws + WS_W2S);
    float*  Rt  = (float*)(ws + WS_R);
    __bf16* Cts = (__bf16*)(ws + WS_CT);

    prep_weights<<<40, 256, 0, stream>>>(W1, W2, w1s, w2s);
    prep_rc<<<64, 256, 0, stream>>>(W1, b1, node, Rt, Cts);
    fused_main<<<512, 256, 0, stream>>>(edge, w1s, w2s, Rt, Cts, b2, W3, b3, (float*)d_out);
}

// Round 7
// 203.991 us; speedup vs baseline: 1.0230x; 1.0230x over previous
//
#include <hip/hip_runtime.h>
#include <stdint.h>

typedef __bf16 bf16x8 __attribute__((ext_vector_type(8)));
typedef __bf16 bf16x4v __attribute__((ext_vector_type(4)));
typedef float  f32x16 __attribute__((ext_vector_type(16)));
typedef float  f32x4t __attribute__((ext_vector_type(4)));
typedef unsigned int u32x2 __attribute__((ext_vector_type(2)));

// ---- ws layout (bytes) ----
#define WS_W1S 0            // 32 chunks  * 1 KB = 32 KB   W1e fragment-swizzled
#define WS_W2S 32768        // 128 chunks * 1 KB = 128 KB  W2 fragment-swizzled
#define WS_R   163840       // 4*256*256 f32 = 1 MiB   Rt[b][n][o] (incl. b1)
#define WS_CT  1212416      // 4*256*256 bf16 = 512 KB Cts fragment-swizzled

// ---------------- combined prep kernel ----------------
// blocks 0..63: R/C rank-1 terms. blocks 64..103: weight swizzle.
__global__ __launch_bounds__(256) void prep_all(
    const float* __restrict__ W1, const float* __restrict__ b1,
    const float* __restrict__ node, const float* __restrict__ W2,
    float* __restrict__ Rt, __bf16* __restrict__ Cts,
    __bf16* __restrict__ w1s, __bf16* __restrict__ w2s) {
    if (blockIdx.x >= 64) {
        int t = (blockIdx.x - 64) * 256 + threadIdx.x;
        int chunk = t >> 6, lane = t & 63;
        if (chunk < 128) {                    // W2: 4 wid x 16 ks x 2 mb
            int wid = chunk >> 5, ks = (chunk >> 1) & 15, mb = chunk & 1;
            int o = wid * 64 + mb * 32 + (lane & 31);
            int k = ks * 16 + (lane >> 5) * 8;
            const float* src = W2 + o * 256 + k;
            __bf16* dst = w2s + chunk * 512 + lane * 8;
#pragma unroll
            for (int j = 0; j < 8; ++j) dst[j] = (__bf16)src[j];
        } else if (chunk < 160) {             // W1e: 4 wid x 4 ks x 2 mb
            int c1 = chunk - 128;
            int wid = c1 >> 3, ks = (c1 >> 1) & 3, mb = c1 & 1;
            int o = wid * 64 + mb * 32 + (lane & 31);
            int k = ks * 16 + (lane >> 5) * 8;
            const float* src = W1 + o * 320 + k;
            __bf16* dst = w1s + c1 * 512 + lane * 8;
#pragma unroll
            for (int j = 0; j < 8; ++j) dst[j] = (__bf16)src[j];
        }
        return;
    }
    __shared__ float nds[128 * 16];
    const int b = blockIdx.x >> 4, j0 = (blockIdx.x & 15) * 16;
    const int o = threadIdx.x;
    {
        int c = threadIdx.x >> 1, jh = (threadIdx.x & 1) * 8;
        const float* src = node + b * 32768 + c * 256 + j0 + jh;
        *(float4*)&nds[c * 16 + jh] = *(const float4*)src;
        *(float4*)&nds[c * 16 + jh + 4] = *(const float4*)(src + 4);
    }
    __syncthreads();
    float aR[16], aC[16];
#pragma unroll
    for (int j = 0; j < 16; ++j) { aR[j] = 0.f; aC[j] = 0.f; }
    const float* wr = W1 + o * 320 + 64;
    const float* wc = W1 + o * 320 + 192;
    for (int c4 = 0; c4 < 32; ++c4) {
        float4 wrv = *(const float4*)(wr + c4 * 4);
        float4 wcv = *(const float4*)(wc + c4 * 4);
        const float* wrp = (const float*)&wrv;
        const float* wcp = (const float*)&wcv;
#pragma unroll
        for (int r = 0; r < 4; ++r) {
            const f32x4t* nrow = (const f32x4t*)&nds[(c4 * 4 + r) * 16];
            f32x4t n0 = nrow[0], n1 = nrow[1], n2 = nrow[2], n3 = nrow[3];
#pragma unroll
            for (int q = 0; q < 4; ++q) {
                aR[q]      = fmaf(wrp[r], n0[q], aR[q]);
                aR[q + 4]  = fmaf(wrp[r], n1[q], aR[q + 4]);
                aR[q + 8]  = fmaf(wrp[r], n2[q], aR[q + 8]);
                aR[q + 12] = fmaf(wrp[r], n3[q], aR[q + 12]);
                aC[q]      = fmaf(wcp[r], n0[q], aC[q]);
                aC[q + 4]  = fmaf(wcp[r], n1[q], aC[q + 4]);
                aC[q + 8]  = fmaf(wcp[r], n2[q], aC[q + 8]);
                aC[q + 12] = fmaf(wcp[r], n3[q], aC[q + 12]);
            }
        }
    }
    float bb = b1[o];
    const int wid = o >> 6, mb = (o >> 5) & 1, rg = (o >> 3) & 3;
    const int hi = (o >> 2) & 1, oq = o & 3;
#pragma unroll
    for (int j = 0; j < 16; ++j) {
        int m = j0 + j;
        Rt[((b * 256 + m) << 8) + o] = aR[j] + bb;
        int mg = m >> 6, nbm = (m >> 5) & 1, p31m = m & 31;
        int chunk = ((((b * 4 + mg) * 4 + wid) * 2 + mb) * 4 + rg) * 2 + nbm;
        Cts[chunk * 256 + (hi * 32 + p31m) * 4 + oq] = (__bf16)aC[j];
    }
}

// ---------------- main fused kernel ----------------
// R5 structure (64-px tiles, no spill: arch ~164 + acc 64 = 228 <= 256
// unified) + stall fixes: (1) edge PREFETCH and first W2 quarter issued
// AFTER bar2 so the barrier's implicit vmcnt(0) drain no longer eats a
// ~900-cyc HBM round trip per tile; (2) A1 persistent in 32 regs (w1s has
// NO anti-LICM barrier; w2 keeps it -- R2/R3: hoisted 128-reg A2 = spill);
// (3) Rt row staged to LDS once per tile (broadcast reads in EPI1);
// (4) h1 XOR-swizzled 512 B rows (conflict-free b64 writes / b128 reads).
__global__ __launch_bounds__(256, 2) void fused_main(
    const float* __restrict__ edge, const __bf16* __restrict__ w1s,
    const __bf16* __restrict__ w2s, const float* __restrict__ Rt,
    const __bf16* __restrict__ Cts, const float* __restrict__ b2,
    const float* __restrict__ W3, const float* __restrict__ b3,
    float* __restrict__ out) {
    __shared__ unsigned int lds_e[64 * 33];   // 8448 B  edge tile [m][e-pair]
    __shared__ unsigned int lds_h1[64 * 128]; // 32768 B h1, xor-swizzled 16B cols
    __shared__ float lds_p[64 * 9];           // 2304 B  layer-3 partials
    __shared__ float lds_c[512];              // 2048 B  b2 | W3
    __shared__ float lds_r[256];              // 1024 B  Rt row n
    char* h1b = (char*)lds_h1;

    const int tid = threadIdx.x;
    const int wid = tid >> 6;
    const int lane = tid & 63;
    const int p31 = lane & 31;
    const int hi = lane >> 5;
    const int obase = wid * 64;

    const int blk = blockIdx.x;
    const int b   = blk >> 7;
    const int mg  = (blk >> 5) & 3;
    const int m0  = mg << 6;
    const int n0  = (blk & 31) << 3;

    lds_c[tid] = b2[tid];
    lds_c[256 + tid] = W3[tid];

    const float4* eg = (const float4*)edge;
    const int a_ = tid & 15;
    const int epb = tid >> 4;
    float4 pf[4];

#define PREFETCH(nn)                                                        \
    {                                                                       \
        _Pragma("unroll")                                                   \
        for (int r = 0; r < 2; ++r) {                                       \
            int ep = r * 16 + epb;                                          \
            int f4 = (b * 64 + ep * 2) * 16384 + (nn) * 64 + (m0 >> 2) + a_;\
            pf[r * 2]     = eg[f4];                                         \
            pf[r * 2 + 1] = eg[f4 + 16384];                                 \
        }                                                                   \
    }

    // quarter A2 load: 4 k-steps x 2 mb = 8 coalesced 16 B loads (32 regs)
#define LOAD_Q(bf, q)                                                       \
    {                                                                       \
        _Pragma("unroll")                                                   \
        for (int ksl = 0; ksl < 4; ++ksl)                                   \
            _Pragma("unroll")                                               \
            for (int mb = 0; mb < 2; ++mb)                                  \
                A2q[bf][ksl][mb] = *(const bf16x8*)(w2_s +                  \
                    ((((wid << 4) + (q) * 4 + ksl) << 1) + mb) * 512 + (lane << 3)); \
    }

    PREFETCH(n0);

    // ---- persistent A1 (W1e) fragments: 32 regs, loaded once ----
    bf16x8 A1[2][4];
#pragma unroll
    for (int mb = 0; mb < 2; ++mb)
#pragma unroll
        for (int ks = 0; ks < 4; ++ks)
            A1[mb][ks] = *(const bf16x8*)(w1s +
                ((((wid << 2) + ks) << 1) + mb) * 512 + (lane << 3));

    // ---- hoisted m-invariant Ct fragments (coalesced, swizzled layout) ----
    bf16x4v CvR[16];
#pragma unroll
    for (int mb = 0; mb < 2; ++mb)
#pragma unroll
        for (int rg = 0; rg < 4; ++rg)
#pragma unroll
            for (int nbm = 0; nbm < 2; ++nbm) {
                int chunk = ((((b * 4 + mg) * 4 + wid) * 2 + mb) * 4 + rg) * 2 + nbm;
                CvR[(mb * 4 + rg) * 2 + nbm] = *(const bf16x4v*)(Cts + chunk * 256 + lane * 4);
            }

    f32x16 acc[2][2];
    bf16x8 A2q[2][4][2];
#pragma unroll 1
    for (int it = 0; it < 8; ++it) {
        const int n = n0 + it;

        // ---- P1: out-store of prev tile + Rt row stage + edge stage ----
        if (it > 0 && tid < 64) {
            float s = b3[0];
#pragma unroll
            for (int k = 0; k < 8; ++k) s += lds_p[tid * 9 + k];
            out[((b * 256 + n - 1) << 8) + m0 + tid] = s;
        }
        if (tid < 64) {
            *(f32x4t*)&lds_r[tid * 4] = *(const f32x4t*)(Rt + ((b * 256 + n) << 8) + tid * 4);
        }
#pragma unroll
        for (int r = 0; r < 2; ++r) {
            int ep = r * 16 + epb;
            const float* p0 = (const float*)&pf[r * 2];
            const float* p1 = (const float*)&pf[r * 2 + 1];
#pragma unroll
            for (int i = 0; i < 4; ++i) {
                union { __bf16 h[2]; unsigned int u; } t;
                t.h[0] = (__bf16)p0[i];
                t.h[1] = (__bf16)p1[i];
                lds_e[(a_ * 4 + i) * 33 + ep] = t.u;
            }
        }
        __syncthreads();                      // bar1 (cheap: LDS only)

        // ---- P2: layer 1 + epilogue 1 ----
#pragma unroll
        for (int mb = 0; mb < 2; ++mb)
#pragma unroll
            for (int nbm = 0; nbm < 2; ++nbm)
#pragma unroll
                for (int k = 0; k < 16; ++k) acc[mb][nbm][k] = 0.f;
#pragma unroll
        for (int ks = 0; ks < 4; ++ks) {
            bf16x8 B1[2];
#pragma unroll
            for (int nbm = 0; nbm < 2; ++nbm) {
                union { unsigned int u[4]; bf16x8 v; } bb;
#pragma unroll
                for (int j = 0; j < 4; ++j)
                    bb.u[j] = lds_e[(nbm * 32 + p31) * 33 + ks * 8 + hi * 4 + j];
                B1[nbm] = bb.v;
            }
#pragma unroll
            for (int mb = 0; mb < 2; ++mb) {
                acc[mb][0] = __builtin_amdgcn_mfma_f32_32x32x16_bf16(A1[mb][ks], B1[0], acc[mb][0], 0, 0, 0);
                acc[mb][1] = __builtin_amdgcn_mfma_f32_32x32x16_bf16(A1[mb][ks], B1[1], acc[mb][1], 0, 0, 0);
            }
        }
        // epilogue 1: + Rt (LDS broadcast) + Ct (regs), relu -> swizzled h1
#pragma unroll
        for (int mb = 0; mb < 2; ++mb) {
#pragma unroll
            for (int rg = 0; rg < 4; ++rg) {
                int och = obase + mb * 32 + 8 * rg + 4 * hi;
                f32x4t Rv = *(const f32x4t*)&lds_r[och];
                int col16 = (wid << 3) + (mb << 2) + rg;
#pragma unroll
                for (int nbm = 0; nbm < 2; ++nbm) {
                    int p = nbm * 32 + p31;
                    bf16x4v Cv = CvR[(mb * 4 + rg) * 2 + nbm];
                    union { __bf16 h[4]; u32x2 u; } t;
#pragma unroll
                    for (int rr = 0; rr < 4; ++rr) {
                        float v = acc[mb][nbm][rg * 4 + rr] + Rv[rr] + (float)Cv[rr];
                        t.h[rr] = (__bf16)fmaxf(v, 0.f);
                    }
                    *(u32x2*)(h1b + p * 512 + ((col16 ^ p31) << 4) + (hi << 3)) = t.u;
                }
            }
        }
        __syncthreads();                      // bar2 (no vm loads in flight)

        // ---- P3: long-latency issues FIRST (drain lands at bar3, covered) ----
        uint64_t w2a = (uint64_t)w2s;
        asm volatile("" : "+s"(w2a));         // anti-LICM: keep W2 streaming
        const __bf16* w2_s = (const __bf16*)w2a;
        if (it < 7) PREFETCH(n + 1);          // cold HBM ~900 cyc, covered by P3
        LOAD_Q(0, 0);

#pragma unroll
        for (int mb = 0; mb < 2; ++mb)
#pragma unroll
            for (int nbm = 0; nbm < 2; ++nbm)
#pragma unroll
                for (int k = 0; k < 16; ++k) acc[mb][nbm][k] = 0.f;
#pragma unroll
        for (int q = 0; q < 4; ++q) {
            if (q < 3) LOAD_Q((q + 1) & 1, q + 1);
#pragma unroll
            for (int ksl = 0; ksl < 4; ++ksl) {
                const int ksg = q * 4 + ksl;
                bf16x8 B2[2];
#pragma unroll
                for (int nbm = 0; nbm < 2; ++nbm) {
                    int p = nbm * 32 + p31;
                    B2[nbm] = *(const bf16x8*)(h1b + p * 512 +
                              ((((ksg << 1) + hi) ^ p31) << 4));
                }
#pragma unroll
                for (int mb = 0; mb < 2; ++mb) {
                    acc[mb][0] = __builtin_amdgcn_mfma_f32_32x32x16_bf16(A2q[q & 1][ksl][mb], B2[0], acc[mb][0], 0, 0, 0);
                    acc[mb][1] = __builtin_amdgcn_mfma_f32_32x32x16_bf16(A2q[q & 1][ksl][mb], B2[1], acc[mb][1], 0, 0, 0);
                }
            }
        }

        // ---- epilogue 2: +b2, relu, dot W3 ----
        float part0 = 0.f, part1 = 0.f;
#pragma unroll
        for (int mb = 0; mb < 2; ++mb) {
#pragma unroll
            for (int rg = 0; rg < 4; ++rg) {
                int och = obase + mb * 32 + 8 * rg + 4 * hi;
                f32x4t b2v = *(const f32x4t*)&lds_c[och];
                f32x4t w3v = *(const f32x4t*)&lds_c[256 + och];
#pragma unroll
                for (int rr = 0; rr < 4; ++rr) {
                    float h0 = fmaxf(acc[mb][0][rg * 4 + rr] + b2v[rr], 0.f);
                    float h1v = fmaxf(acc[mb][1][rg * 4 + rr] + b2v[rr], 0.f);
                    part0 = fmaf(w3v[rr], h0, part0);
                    part1 = fmaf(w3v[rr], h1v, part1);
                }
            }
        }
        lds_p[(0 * 32 + p31) * 9 + wid * 2 + hi] = part0;
        lds_p[(1 * 32 + p31) * 9 + wid * 2 + hi] = part1;
        __syncthreads();                      // bar3 (drains pf residue + lds)
    }

    // final tile's output
    if (tid < 64) {
        float s = b3[0];
#pragma unroll
        for (int k = 0; k < 8; ++k) s += lds_p[tid * 9 + k];
        out[((b * 256 + n0 + 7) << 8) + m0 + tid] = s;
    }
#undef PREFETCH
#undef LOAD_Q
}

extern "C" void kernel_launch(void* const* d_in, const int* in_sizes, int n_in,
                              void* d_out, int out_size, void* d_ws, size_t ws_size,
                              hipStream_t stream) {
    const float* edge = (const float*)d_in[0];
    const float* node = (const float*)d_in[1];
    const float* W1   = (const float*)d_in[2];
    const float* b1   = (const float*)d_in[3];
    const float* W2   = (const float*)d_in[4];
    const float* b2   = (const float*)d_in[5];
    const float* W3   = (const float*)d_in[6];
    const float* b3   = (const float*)d_in[7];
    char* ws = (char*)d_ws;
    __bf16* w1s = (__bf16*)(ws + WS_W1S);
    __bf16* w2s = (__bf16*)(ws + WS_W2S);
    float*  Rt  = (float*)(ws + WS_R);
    __bf16* Cts = (__bf16*)(ws + WS_CT);

    prep_all<<<104, 256, 0, stream>>>(W1, b1, node, W2, Rt, Cts, w1s, w2s);
    fused_main<<<512, 256, 0, stream>>>(edge, w1s, w2s, Rt, Cts, b2, W3, b3, (float*)d_out);
}

// Round 8
// 165.307 us; speedup vs baseline: 1.2624x; 1.2340x over previous
//
#include <hip/hip_runtime.h>
#include <stdint.h>

typedef __bf16 bf16x8 __attribute__((ext_vector_type(8)));
typedef __bf16 bf16x4v __attribute__((ext_vector_type(4)));
typedef float  f32x16 __attribute__((ext_vector_type(16)));
typedef float  f32x4t __attribute__((ext_vector_type(4)));
typedef unsigned int u32x2 __attribute__((ext_vector_type(2)));

// ---- ws layout (bytes) ----
#define WS_W1S 0            // 32 chunks  * 1 KB = 32 KB   W1e fragment-swizzled
#define WS_W2S 32768        // 128 chunks * 1 KB = 128 KB  W2 fragment-swizzled
#define WS_R   163840       // 4*256*256 f32 = 1 MiB   Rt[b][n][o] (incl. b1)
#define WS_CT  1212416      // 4*256*256 bf16 = 512 KB Cts fragment-swizzled

// ---------------- combined prep kernel ----------------
// blocks 0..63: R/C rank-1 terms. blocks 64..103: weight swizzle.
__global__ __launch_bounds__(256) void prep_all(
    const float* __restrict__ W1, const float* __restrict__ b1,
    const float* __restrict__ node, const float* __restrict__ W2,
    float* __restrict__ Rt, __bf16* __restrict__ Cts,
    __bf16* __restrict__ w1s, __bf16* __restrict__ w2s) {
    if (blockIdx.x >= 64) {
        int t = (blockIdx.x - 64) * 256 + threadIdx.x;
        int chunk = t >> 6, lane = t & 63;
        if (chunk < 128) {                    // W2: 4 wid x 16 ks x 2 mb
            int wid = chunk >> 5, ks = (chunk >> 1) & 15, mb = chunk & 1;
            int o = wid * 64 + mb * 32 + (lane & 31);
            int k = ks * 16 + (lane >> 5) * 8;
            const float* src = W2 + o * 256 + k;
            __bf16* dst = w2s + chunk * 512 + lane * 8;
#pragma unroll
            for (int j = 0; j < 8; ++j) dst[j] = (__bf16)src[j];
        } else if (chunk < 160) {             // W1e: 4 wid x 4 ks x 2 mb
            int c1 = chunk - 128;
            int wid = c1 >> 3, ks = (c1 >> 1) & 3, mb = c1 & 1;
            int o = wid * 64 + mb * 32 + (lane & 31);
            int k = ks * 16 + (lane >> 5) * 8;
            const float* src = W1 + o * 320 + k;
            __bf16* dst = w1s + c1 * 512 + lane * 8;
#pragma unroll
            for (int j = 0; j < 8; ++j) dst[j] = (__bf16)src[j];
        }
        return;
    }
    __shared__ float nds[128 * 16];
    const int b = blockIdx.x >> 4, j0 = (blockIdx.x & 15) * 16;
    const int o = threadIdx.x;
    {
        int c = threadIdx.x >> 1, jh = (threadIdx.x & 1) * 8;
        const float* src = node + b * 32768 + c * 256 + j0 + jh;
        *(float4*)&nds[c * 16 + jh] = *(const float4*)src;
        *(float4*)&nds[c * 16 + jh + 4] = *(const float4*)(src + 4);
    }
    __syncthreads();
    float aR[16], aC[16];
#pragma unroll
    for (int j = 0; j < 16; ++j) { aR[j] = 0.f; aC[j] = 0.f; }
    const float* wr = W1 + o * 320 + 64;
    const float* wc = W1 + o * 320 + 192;
    for (int c4 = 0; c4 < 32; ++c4) {
        float4 wrv = *(const float4*)(wr + c4 * 4);
        float4 wcv = *(const float4*)(wc + c4 * 4);
        const float* wrp = (const float*)&wrv;
        const float* wcp = (const float*)&wcv;
#pragma unroll
        for (int r = 0; r < 4; ++r) {
            const f32x4t* nrow = (const f32x4t*)&nds[(c4 * 4 + r) * 16];
            f32x4t n0 = nrow[0], n1 = nrow[1], n2 = nrow[2], n3 = nrow[3];
#pragma unroll
            for (int q = 0; q < 4; ++q) {
                aR[q]      = fmaf(wrp[r], n0[q], aR[q]);
                aR[q + 4]  = fmaf(wrp[r], n1[q], aR[q + 4]);
                aR[q + 8]  = fmaf(wrp[r], n2[q], aR[q + 8]);
                aR[q + 12] = fmaf(wrp[r], n3[q], aR[q + 12]);
                aC[q]      = fmaf(wcp[r], n0[q], aC[q]);
                aC[q + 4]  = fmaf(wcp[r], n1[q], aC[q + 4]);
                aC[q + 8]  = fmaf(wcp[r], n2[q], aC[q + 8]);
                aC[q + 12] = fmaf(wcp[r], n3[q], aC[q + 12]);
            }
        }
    }
    float bb = b1[o];
    const int wid = o >> 6, mb = (o >> 5) & 1, rg = (o >> 3) & 3;
    const int hi = (o >> 2) & 1, oq = o & 3;
#pragma unroll
    for (int j = 0; j < 16; ++j) {
        int m = j0 + j;
        Rt[((b * 256 + m) << 8) + o] = aR[j] + bb;
        int mg = m >> 6, nbm = (m >> 5) & 1, p31m = m & 31;
        int chunk = ((((b * 4 + mg) * 4 + wid) * 2 + mb) * 4 + rg) * 2 + nbm;
        Cts[chunk * 256 + (hi * 32 + p31m) * 4 + oq] = (__bf16)aC[j];
    }
}

// ---------------- main fused kernel ----------------
// EXACTLY the R5 structure (64-px tiles; arch ~125 <= 128 hard cap, acc 64
// AGPR; no spill) with ONE change: edge PREFETCH + first W2 quarter are
// issued AFTER bar2 (start of layer-2) instead of before it, so bar2's
// implicit vmcnt(0) no longer drains a ~900-cyc HBM round trip with all
// 8 waves/CU stalled; the drain now lands at bar3 behind ~1000 cyc of
// layer-2 MFMA. A1/A2 remain streamed per tile behind asm anti-LICM
// barriers (R2/R3/R7 lesson: any persistent weight array >0 regs beyond
// this budget -> scratch spill, WRITE_SIZE balloons).
__global__ __launch_bounds__(256, 2) void fused_main(
    const float* __restrict__ edge, const __bf16* __restrict__ w1s,
    const __bf16* __restrict__ w2s, const float* __restrict__ Rt,
    const __bf16* __restrict__ Cts, const float* __restrict__ b2,
    const float* __restrict__ W3, const float* __restrict__ b3,
    float* __restrict__ out) {
    __shared__ unsigned int lds_e[64 * 33];   // 8448 B  edge tile [m][e-pair]
    __shared__ unsigned int lds_h1[64 * 128]; // 32768 B h1, xor-swizzled 16B cols
    __shared__ float lds_p[64 * 9];           // 2304 B  layer-3 partials
    __shared__ float lds_c[512];              // 2048 B  b2 | W3
    char* h1b = (char*)lds_h1;

    const int tid = threadIdx.x;
    const int wid = tid >> 6;
    const int lane = tid & 63;
    const int p31 = lane & 31;
    const int hi = lane >> 5;
    const int obase = wid * 64;

    const int blk = blockIdx.x;
    const int b   = blk >> 7;
    const int mg  = (blk >> 5) & 3;
    const int m0  = mg << 6;
    const int n0  = (blk & 31) << 3;

    lds_c[tid] = b2[tid];
    lds_c[256 + tid] = W3[tid];

    const float4* eg = (const float4*)edge;
    const int a_ = tid & 15;
    const int epb = tid >> 4;
    float4 pf[4];

#define PREFETCH(nn)                                                        \
    {                                                                       \
        _Pragma("unroll")                                                   \
        for (int r = 0; r < 2; ++r) {                                       \
            int ep = r * 16 + epb;                                          \
            int f4 = (b * 64 + ep * 2) * 16384 + (nn) * 64 + (m0 >> 2) + a_;\
            pf[r * 2]     = eg[f4];                                         \
            pf[r * 2 + 1] = eg[f4 + 16384];                                 \
        }                                                                   \
    }

    // quarter A2 load: 4 k-steps x 2 mb = 8 coalesced 16 B loads (32 regs)
#define LOAD_Q(bf, q)                                                       \
    {                                                                       \
        _Pragma("unroll")                                                   \
        for (int ksl = 0; ksl < 4; ++ksl)                                   \
            _Pragma("unroll")                                               \
            for (int mb = 0; mb < 2; ++mb)                                  \
                A2q[bf][ksl][mb] = *(const bf16x8*)(w2_s +                  \
                    ((((wid << 4) + (q) * 4 + ksl) << 1) + mb) * 512 + (lane << 3)); \
    }

    PREFETCH(n0);

    // ---- hoisted m-invariant Ct fragments (coalesced, swizzled layout) ----
    bf16x4v CvR[16];
#pragma unroll
    for (int mb = 0; mb < 2; ++mb)
#pragma unroll
        for (int rg = 0; rg < 4; ++rg)
#pragma unroll
            for (int nbm = 0; nbm < 2; ++nbm) {
                int chunk = ((((b * 4 + mg) * 4 + wid) * 2 + mb) * 4 + rg) * 2 + nbm;
                CvR[(mb * 4 + rg) * 2 + nbm] = *(const bf16x4v*)(Cts + chunk * 256 + lane * 4);
            }

    f32x16 acc[2][2];
    bf16x8 A2q[2][4][2];
#pragma unroll 1
    for (int it = 0; it < 8; ++it) {
        const int n = n0 + it;

        // opaque per-iteration address barriers (defeat LICM/CSE of weight loads)
        uint64_t w1a = (uint64_t)w1s;
        asm volatile("" : "+s"(w1a));
        const __bf16* w1_s = (const __bf16*)w1a;
        uint64_t w2a = (uint64_t)w2s;
        asm volatile("" : "+s"(w2a));
        const __bf16* w2_s = (const __bf16*)w2a;

        // ---- P1: stage pf -> lds_e (transpose to [m][e], bf16) ----
#pragma unroll
        for (int r = 0; r < 2; ++r) {
            int ep = r * 16 + epb;
            const float* p0 = (const float*)&pf[r * 2];
            const float* p1 = (const float*)&pf[r * 2 + 1];
#pragma unroll
            for (int i = 0; i < 4; ++i) {
                union { __bf16 h[2]; unsigned int u; } t;
                t.h[0] = (__bf16)p0[i];
                t.h[1] = (__bf16)p1[i];
                lds_e[(a_ * 4 + i) * 33 + ep] = t.u;
            }
        }
        // A1 (W1e) fragments: streamed from L2 this tile (transient 32 regs)
        bf16x8 A1[2][4];
#pragma unroll
        for (int mb = 0; mb < 2; ++mb)
#pragma unroll
            for (int ks = 0; ks < 4; ++ks)
                A1[mb][ks] = *(const bf16x8*)(w1_s +
                    ((((wid << 2) + ks) << 1) + mb) * 512 + (lane << 3));
        __syncthreads();                      // bar1

        // ---- P2: layer 1 ----
#pragma unroll
        for (int mb = 0; mb < 2; ++mb)
#pragma unroll
            for (int nbm = 0; nbm < 2; ++nbm)
#pragma unroll
                for (int k = 0; k < 16; ++k) acc[mb][nbm][k] = 0.f;
#pragma unroll
        for (int ks = 0; ks < 4; ++ks) {
            bf16x8 B1[2];
#pragma unroll
            for (int nbm = 0; nbm < 2; ++nbm) {
                union { unsigned int u[4]; bf16x8 v; } bb;
#pragma unroll
                for (int j = 0; j < 4; ++j)
                    bb.u[j] = lds_e[(nbm * 32 + p31) * 33 + ks * 8 + hi * 4 + j];
                B1[nbm] = bb.v;
            }
#pragma unroll
            for (int mb = 0; mb < 2; ++mb) {
                acc[mb][0] = __builtin_amdgcn_mfma_f32_32x32x16_bf16(A1[mb][ks], B1[0], acc[mb][0], 0, 0, 0);
                acc[mb][1] = __builtin_amdgcn_mfma_f32_32x32x16_bf16(A1[mb][ks], B1[1], acc[mb][1], 0, 0, 0);
            }
        }
        // epilogue 1: + Rt[n] (broadcast L2) + Ct (regs), relu -> swizzled h1
        const int nRow = (b * 256 + n) << 8;
#pragma unroll
        for (int mb = 0; mb < 2; ++mb) {
#pragma unroll
            for (int rg = 0; rg < 4; ++rg) {
                int och = obase + mb * 32 + 8 * rg + 4 * hi;
                f32x4t Rv = *(const f32x4t*)(Rt + nRow + och);
                int col16 = (wid << 3) + (mb << 2) + rg;
#pragma unroll
                for (int nbm = 0; nbm < 2; ++nbm) {
                    int p = nbm * 32 + p31;
                    bf16x4v Cv = CvR[(mb * 4 + rg) * 2 + nbm];
                    union { __bf16 h[4]; u32x2 u; } t;
#pragma unroll
                    for (int rr = 0; rr < 4; ++rr) {
                        float v = acc[mb][nbm][rg * 4 + rr] + Rv[rr] + (float)Cv[rr];
                        t.h[rr] = (__bf16)fmaxf(v, 0.f);
                    }
                    *(u32x2*)(h1b + p * 512 + ((col16 ^ p31) << 4) + (hi << 3)) = t.u;
                }
            }
        }
        __syncthreads();                      // bar2 (no vm loads in flight now)

        // ---- P3: long-latency issues FIRST, drained at bar3 under MFMA cover ----
        if (it < 7) PREFETCH(n + 1);          // cold HBM ~900 cyc
        LOAD_Q(0, 0);                         // first W2 quarter (L2)

#pragma unroll
        for (int mb = 0; mb < 2; ++mb)
#pragma unroll
            for (int nbm = 0; nbm < 2; ++nbm)
#pragma unroll
                for (int k = 0; k < 16; ++k) acc[mb][nbm][k] = 0.f;
#pragma unroll
        for (int q = 0; q < 4; ++q) {
            if (q < 3) LOAD_Q((q + 1) & 1, q + 1);
#pragma unroll
            for (int ksl = 0; ksl < 4; ++ksl) {
                const int ksg = q * 4 + ksl;
                bf16x8 B2[2];
#pragma unroll
                for (int nbm = 0; nbm < 2; ++nbm) {
                    int p = nbm * 32 + p31;
                    B2[nbm] = *(const bf16x8*)(h1b + p * 512 +
                              ((((ksg << 1) + hi) ^ p31) << 4));
                }
#pragma unroll
                for (int mb = 0; mb < 2; ++mb) {
                    acc[mb][0] = __builtin_amdgcn_mfma_f32_32x32x16_bf16(A2q[q & 1][ksl][mb], B2[0], acc[mb][0], 0, 0, 0);
                    acc[mb][1] = __builtin_amdgcn_mfma_f32_32x32x16_bf16(A2q[q & 1][ksl][mb], B2[1], acc[mb][1], 0, 0, 0);
                }
            }
        }

        // ---- epilogue 2: +b2, relu, dot W3 ----
        float part0 = 0.f, part1 = 0.f;
#pragma unroll
        for (int mb = 0; mb < 2; ++mb) {
#pragma unroll
            for (int rg = 0; rg < 4; ++rg) {
                int och = obase + mb * 32 + 8 * rg + 4 * hi;
                f32x4t b2v = *(const f32x4t*)&lds_c[och];
                f32x4t w3v = *(const f32x4t*)&lds_c[256 + och];
#pragma unroll
                for (int rr = 0; rr < 4; ++rr) {
                    float h0 = fmaxf(acc[mb][0][rg * 4 + rr] + b2v[rr], 0.f);
                    float h1v = fmaxf(acc[mb][1][rg * 4 + rr] + b2v[rr], 0.f);
                    part0 = fmaf(w3v[rr], h0, part0);
                    part1 = fmaf(w3v[rr], h1v, part1);
                }
            }
        }
        lds_p[(0 * 32 + p31) * 9 + wid * 2 + hi] = part0;
        lds_p[(1 * 32 + p31) * 9 + wid * 2 + hi] = part1;
        __syncthreads();                      // bar3 (drains pf + A2q residue)

        if (tid < 64) {
            float s = b3[0];
#pragma unroll
            for (int k = 0; k < 8; ++k) s += lds_p[tid * 9 + k];
            out[((b * 256 + n) << 8) + m0 + tid] = s;
        }
    }
#undef PREFETCH
#undef LOAD_Q
}

extern "C" void kernel_launch(void* const* d_in, const int* in_sizes, int n_in,
                              void* d_out, int out_size, void* d_ws, size_t ws_size,
                              hipStream_t stream) {
    const float* edge = (const float*)d_in[0];
    const float* node = (const float*)d_in[1];
    const float* W1   = (const float*)d_in[2];
    const float* b1   = (const float*)d_in[3];
    const float* W2   = (const float*)d_in[4];
    const float* b2   = (const float*)d_in[5];
    const float* W3   = (const float*)d_in[6];
    const float* b3   = (const float*)d_in[7];
    char* ws = (char*)d_ws;
    __bf16* w1s = (__bf16*)(ws + WS_W1S);
    __bf16* w2s = (__bf16*)(ws + WS_W2S);
    float*  Rt  = (float*)(ws + WS_R);
    __bf16* Cts = (__bf16*)(ws + WS_CT);

    prep_all<<<104, 256, 0, stream>>>(W1, b1, node, W2, Rt, Cts, w1s, w2s);
    fused_main<<<512, 256, 0, stream>>>(edge, w1s, w2s, Rt, Cts, b2, W3, b3, (float*)d_out);
}